// Round 1
// baseline (265.359 us; speedup 1.0000x reference)
//
#include <hip/hip_runtime.h>

typedef unsigned short u16;
typedef __attribute__((ext_vector_type(8))) short bf16x8;
typedef __attribute__((ext_vector_type(4))) float f32x4;

#define N_PAT 4096
#define KDIM  1024
#define NMOD  4
#define DDIM  256
#define NTILE 32              // N_PAT / 128
#define NPAIR 528             // NTILE*(NTILE+1)/2

static __device__ __forceinline__ u16 f2bf(float x) {
  unsigned int u = __builtin_bit_cast(unsigned int, x);
  u += 0x7FFFu + ((u >> 16) & 1u);   // RNE (inputs are finite normals)
  return (u16)(u >> 16);
}

// ---------------------------------------------------------------------------
// prep: per (m,i) row -> norm, missing flag, bf16 normalized+masked embedding
// Y layout: [i][m*256+d]  (K-concatenated modalities), a/b tables fp32
// ---------------------------------------------------------------------------
__global__ __launch_bounds__(256) void prep_kernel(
    const float* __restrict__ eb, u16* __restrict__ Y,
    float* __restrict__ a_tab, float* __restrict__ b_tab)
{
  int wid  = threadIdx.x >> 6;
  int lane = threadIdx.x & 63;
  int row  = blockIdx.x * 4 + wid;          // row = m*4096 + i
  int m = row >> 12;
  int i = row & (N_PAT - 1);
  const float* base = eb + (size_t)row * DDIM;
  float4 v = *(const float4*)(base + lane * 4);
  float x0 = base[0];
  int eq = (v.x == x0) & (v.y == x0) & (v.z == x0) & (v.w == x0);
  float ss = v.x * v.x + v.y * v.y + v.z * v.z + v.w * v.w;
#pragma unroll
  for (int o = 32; o; o >>= 1) ss += __shfl_xor(ss, o, 64);
  int missing = __all(eq);
  float nrm   = sqrtf(ss);
  float denom = fmaxf(nrm, 1e-8f);
  float inv   = missing ? 0.0f : (1.0f / denom);
  ushort4 o4;
  o4.x = f2bf(v.x * inv); o4.y = f2bf(v.y * inv);
  o4.z = f2bf(v.z * inv); o4.w = f2bf(v.w * inv);
  *(ushort4*)(Y + (size_t)i * KDIM + m * DDIM + lane * 4) = o4;
  if (lane == 0) {
    float ssim = ss / (denom * denom);       // self-cosine (== ref diagonal)
    a_tab[m * N_PAT + i] = missing ? 0.0f : ssim;
    b_tab[m * N_PAT + i] = missing ? 0.0f : 1.0f;
  }
}

// ---------------------------------------------------------------------------
// cox_sumexp: sumexp[i] = sum_j [t_j >= t_i] * exp(h_j)
// ---------------------------------------------------------------------------
__global__ __launch_bounds__(256) void cox_sumexp_kernel(
    const float* __restrict__ t, const float* __restrict__ h,
    float* __restrict__ sumexp)
{
  __shared__ float tl[N_PAT];
  __shared__ float eh[N_PAT];
  for (int q = threadIdx.x; q < N_PAT; q += 256) { tl[q] = t[q]; eh[q] = expf(h[q]); }
  __syncthreads();
  int i = blockIdx.x * 256 + threadIdx.x;
  float ti = tl[i];
  float s = 0.0f;
  for (int j = 0; j < N_PAT; ++j) s += (tl[j] >= ti) ? eh[j] : 0.0f;
  sumexp[i] = s;
}

// ---------------------------------------------------------------------------
// gemm_sim: triangular-tiled Yn @ Yn^T with fused relu-reduction epilogue.
// 128x128 tile, 4 waves (2x2), 4x4 frags of mfma_f32_16x16x32_bf16, BK=32.
// ---------------------------------------------------------------------------
__global__ __launch_bounds__(256) void gemm_sim_kernel(
    const u16* __restrict__ Y,
    const float* __restrict__ a_tab, const float* __restrict__ b_tab,
    const float* __restrict__ Mp, float* __restrict__ partials)
{
  __shared__ u16 At[128 * 32];
  __shared__ u16 Bt[128 * 32];
  __shared__ float aRs[NMOD][128], bRs[NMOD][128];
  __shared__ float aCs[NMOD][128], bCs[NMOD][128];
  __shared__ float redbuf[4];

  int p = blockIdx.x;
  int by = (int)((sqrtf(8.0f * (float)p + 1.0f) - 1.0f) * 0.5f);
  while ((by + 1) * (by + 2) / 2 <= p) ++by;
  while (by * (by + 1) / 2 > p) --by;
  int bx = p - by * (by + 1) / 2;            // bx <= by
  int brow = bx * 128, bcol = by * 128;

  int tid  = threadIdx.x;
  int lane = tid & 63;
  int wid  = tid >> 6;
  int wr = wid >> 1, wc = wid & 1;

  if (tid < 128) {
#pragma unroll
    for (int m = 0; m < NMOD; ++m) {
      aRs[m][tid] = a_tab[m * N_PAT + brow + tid];
      bRs[m][tid] = b_tab[m * N_PAT + brow + tid];
      aCs[m][tid] = a_tab[m * N_PAT + bcol + tid];
      bCs[m][tid] = b_tab[m * N_PAT + bcol + tid];
    }
  }

  const f32x4 zero = {0.f, 0.f, 0.f, 0.f};
  f32x4 acc[4][4];
#pragma unroll
  for (int a = 0; a < 4; ++a)
#pragma unroll
    for (int b = 0; b < 4; ++b) acc[a][b] = zero;

  for (int k = 0; k < KDIM; k += 32) {
    __syncthreads();                          // LDS reuse fence (also covers ab-tables 1st iter)
#pragma unroll
    for (int t = 0; t < 2; ++t) {
      int q = tid + t * 256;                  // 512 slots of 16B per tile
      int r = q >> 2, cs = q & 3;
      const u16* gA = Y + (size_t)(brow + r) * KDIM + k + cs * 8;
      const u16* gB = Y + (size_t)(bcol + r) * KDIM + k + cs * 8;
      __builtin_amdgcn_global_load_lds(
          (const __attribute__((address_space(1))) void*)gA,
          (__attribute__((address_space(3))) void*)(&At[q * 8]), 16, 0, 0);
      __builtin_amdgcn_global_load_lds(
          (const __attribute__((address_space(1))) void*)gB,
          (__attribute__((address_space(3))) void*)(&Bt[q * 8]), 16, 0, 0);
    }
    __syncthreads();                          // drains vmcnt before reads

    bf16x8 af[4], bfv[4];
#pragma unroll
    for (int mi = 0; mi < 4; ++mi) {
      int r = wr * 64 + mi * 16 + (lane & 15);
      af[mi] = *(const bf16x8*)(&At[r * 32 + (lane >> 4) * 8]);
    }
#pragma unroll
    for (int ni = 0; ni < 4; ++ni) {
      int c = wc * 64 + ni * 16 + (lane & 15);
      bfv[ni] = *(const bf16x8*)(&Bt[c * 32 + (lane >> 4) * 8]);
    }
#pragma unroll
    for (int mi = 0; mi < 4; ++mi)
#pragma unroll
      for (int ni = 0; ni < 4; ++ni)
        acc[mi][ni] = __builtin_amdgcn_mfma_f32_16x16x32_bf16(
            af[mi], bfv[ni], acc[mi][ni], 0, 0, 0);
  }

  // Epilogue: term(i,j) = relu(M - msim + psim_ij), + mirrored term for off-diag tiles
  float Mv = Mp[0];
  float lsum = 0.0f;
  bool offd = (bx != by);
#pragma unroll
  for (int mi = 0; mi < 4; ++mi) {
#pragma unroll
    for (int ni = 0; ni < 4; ++ni) {
#pragma unroll
      for (int j = 0; j < 4; ++j) {
        int il = wr * 64 + mi * 16 + ((lane >> 4) << 2) + j;  // C row (local)
        int jl = wc * 64 + ni * 16 + (lane & 15);             // C col (local)
        float msim = acc[mi][ni][j];
        float p1 = 0.f;
#pragma unroll
        for (int m = 0; m < NMOD; ++m) p1 += aRs[m][il] * bCs[m][jl];
        float t1 = Mv - msim + p1;
        if ((brow + il) != (bcol + jl) && t1 > 0.f) lsum += t1;
        if (offd) {
          float p2 = 0.f;
#pragma unroll
          for (int m = 0; m < NMOD; ++m) p2 += aCs[m][jl] * bRs[m][il];
          float t2 = Mv - msim + p2;
          if (t2 > 0.f) lsum += t2;
        }
      }
    }
  }
#pragma unroll
  for (int o = 32; o; o >>= 1) lsum += __shfl_xor(lsum, o, 64);
  if (lane == 0) redbuf[wid] = lsum;
  __syncthreads();
  if (tid == 0) partials[p] = redbuf[0] + redbuf[1] + redbuf[2] + redbuf[3];
}

// ---------------------------------------------------------------------------
// finalize: cox = -sum(ev*(h - log(sumexp)))/sum(ev); out = cox + sum(partials)
// ---------------------------------------------------------------------------
__global__ __launch_bounds__(256) void finalize_kernel(
    const float* __restrict__ h, const int* __restrict__ ev,
    const float* __restrict__ sumexp, const float* __restrict__ partials,
    float* __restrict__ out)
{
  __shared__ float rb[12];
  int tid = threadIdx.x, lane = tid & 63, wid = tid >> 6;
  float num = 0.f, den = 0.f, sim = 0.f;
  for (int i = tid; i < N_PAT; i += 256) {
    float e = (float)ev[i];
    num += e * (h[i] - logf(sumexp[i]));
    den += e;
  }
  for (int q = tid; q < NPAIR; q += 256) sim += partials[q];
#pragma unroll
  for (int o = 32; o; o >>= 1) {
    num += __shfl_xor(num, o, 64);
    den += __shfl_xor(den, o, 64);
    sim += __shfl_xor(sim, o, 64);
  }
  if (lane == 0) { rb[wid] = num; rb[4 + wid] = den; rb[8 + wid] = sim; }
  __syncthreads();
  if (tid == 0) {
    float n = rb[0] + rb[1] + rb[2] + rb[3];
    float d = rb[4] + rb[5] + rb[6] + rb[7];
    float s = rb[8] + rb[9] + rb[10] + rb[11];
    out[0] = -n / d + s;
  }
}

// ---------------------------------------------------------------------------
extern "C" void kernel_launch(void* const* d_in, const int* in_sizes, int n_in,
                              void* d_out, int out_size, void* d_ws, size_t ws_size,
                              hipStream_t stream)
{
  const float* h  = (const float*)d_in[0];
  const float* eb = (const float*)d_in[1];
  const float* tm = (const float*)d_in[2];
  const int*   ev = (const int*)d_in[3];
  const float* Mp = (const float*)d_in[4];
  float* out = (float*)d_out;

  char* ws = (char*)d_ws;
  u16*   Y        = (u16*)ws;                                   // 8 MB
  float* a_tab    = (float*)(ws + (size_t)8 * 1024 * 1024);     // 64 KB
  float* b_tab    = a_tab + NMOD * N_PAT;                       // 64 KB
  float* sumexp   = b_tab + NMOD * N_PAT;                       // 16 KB
  float* partials = sumexp + N_PAT;                             // 528 floats

  prep_kernel<<<dim3(N_PAT * NMOD / 4), dim3(256), 0, stream>>>(eb, Y, a_tab, b_tab);
  cox_sumexp_kernel<<<dim3(N_PAT / 256), dim3(256), 0, stream>>>(tm, h, sumexp);
  gemm_sim_kernel<<<dim3(NPAIR), dim3(256), 0, stream>>>(Y, a_tab, b_tab, Mp, partials);
  finalize_kernel<<<dim3(1), dim3(256), 0, stream>>>(h, ev, sumexp, partials, out);
}

// Round 2
// 58.213 us; speedup vs baseline: 4.5584x; 4.5584x over previous
//
#include <hip/hip_runtime.h>

typedef unsigned short u16;
typedef __attribute__((ext_vector_type(8))) short bf16x8;
typedef __attribute__((ext_vector_type(4))) float f32x4;

#define N_PAT 4096
#define KDIM  1024
#define NMOD  4
#define DDIM  256
#define NTILE 32              // N_PAT / 128
#define NPAIR 528             // NTILE*(NTILE+1)/2

static __device__ __forceinline__ u16 f2bf(float x) {
  unsigned int u = __builtin_bit_cast(unsigned int, x);
  u += 0x7FFFu + ((u >> 16) & 1u);   // RNE (inputs are finite normals)
  return (u16)(u >> 16);
}

// ---------------------------------------------------------------------------
// prep: per (m,i) row -> norm, missing flag, bf16 normalized+masked embedding
// Y layout: [i][m*256+d]  (K-concatenated modalities), a/b tables fp32.
// Blocks 0..15 additionally precompute eh[q] = exp(h[q]).
// ---------------------------------------------------------------------------
__global__ __launch_bounds__(256) void prep_kernel(
    const float* __restrict__ eb, const float* __restrict__ h,
    u16* __restrict__ Y, float* __restrict__ a_tab, float* __restrict__ b_tab,
    float* __restrict__ eh)
{
  if (blockIdx.x < 16) {
    int q = blockIdx.x * 256 + threadIdx.x;
    eh[q] = expf(h[q]);
  }
  int wid  = threadIdx.x >> 6;
  int lane = threadIdx.x & 63;
  int row  = blockIdx.x * 4 + wid;          // row = m*4096 + i
  int m = row >> 12;
  int i = row & (N_PAT - 1);
  const float* base = eb + (size_t)row * DDIM;
  float4 v = *(const float4*)(base + lane * 4);
  float x0 = base[0];
  int eq = (v.x == x0) & (v.y == x0) & (v.z == x0) & (v.w == x0);
  float ss = v.x * v.x + v.y * v.y + v.z * v.z + v.w * v.w;
#pragma unroll
  for (int o = 32; o; o >>= 1) ss += __shfl_xor(ss, o, 64);
  int missing = __all(eq);
  float nrm   = sqrtf(ss);
  float denom = fmaxf(nrm, 1e-8f);
  float inv   = missing ? 0.0f : (1.0f / denom);
  ushort4 o4;
  o4.x = f2bf(v.x * inv); o4.y = f2bf(v.y * inv);
  o4.z = f2bf(v.z * inv); o4.w = f2bf(v.w * inv);
  *(ushort4*)(Y + (size_t)i * KDIM + m * DDIM + lane * 4) = o4;
  if (lane == 0) {
    float ssim = ss / (denom * denom);       // self-cosine (== ref diagonal)
    a_tab[m * N_PAT + i] = missing ? 0.0f : ssim;
    b_tab[m * N_PAT + i] = missing ? 0.0f : 1.0f;
  }
}

// ---------------------------------------------------------------------------
// cox_sumexp: sumexp[i] = sum_j [t_j >= t_i] * eh[j]. One wave per i.
// 1024 blocks x 256 thr; per lane 16 float4-iterations; t/eh are L1-resident.
// ---------------------------------------------------------------------------
__global__ __launch_bounds__(256) void cox_sumexp_kernel(
    const float* __restrict__ t, const float* __restrict__ eh,
    float* __restrict__ sumexp)
{
  int wid = threadIdx.x >> 6, lane = threadIdx.x & 63;
  int i = blockIdx.x * 4 + wid;
  float ti = t[i];
  float s = 0.f;
#pragma unroll
  for (int it = 0; it < 16; ++it) {
    int j = (it * 64 + lane) * 4;
    float4 tv = *(const float4*)(t + j);
    float4 ev = *(const float4*)(eh + j);
    s += (tv.x >= ti) ? ev.x : 0.f;
    s += (tv.y >= ti) ? ev.y : 0.f;
    s += (tv.z >= ti) ? ev.z : 0.f;
    s += (tv.w >= ti) ? ev.w : 0.f;
  }
#pragma unroll
  for (int o = 32; o; o >>= 1) s += __shfl_xor(s, o, 64);
  if (lane == 0) sumexp[i] = s;
}

// ---------------------------------------------------------------------------
// gemm_sim: triangular-tiled Yn @ Yn^T with fused relu-reduction epilogue.
// 128x128 tile, 4 waves (2x2), 4x4 frags of mfma_f32_16x16x32_bf16, BK=32.
// ---------------------------------------------------------------------------
__global__ __launch_bounds__(256) void gemm_sim_kernel(
    const u16* __restrict__ Y,
    const float* __restrict__ a_tab, const float* __restrict__ b_tab,
    const float* __restrict__ Mp, float* __restrict__ partials)
{
  __shared__ u16 At[128 * 32];
  __shared__ u16 Bt[128 * 32];
  __shared__ float aRs[NMOD][128], bRs[NMOD][128];
  __shared__ float aCs[NMOD][128], bCs[NMOD][128];
  __shared__ float redbuf[4];

  int p = blockIdx.x;
  int by = (int)((sqrtf(8.0f * (float)p + 1.0f) - 1.0f) * 0.5f);
  while ((by + 1) * (by + 2) / 2 <= p) ++by;
  while (by * (by + 1) / 2 > p) --by;
  int bx = p - by * (by + 1) / 2;            // bx <= by
  int brow = bx * 128, bcol = by * 128;

  int tid  = threadIdx.x;
  int lane = tid & 63;
  int wid  = tid >> 6;
  int wr = wid >> 1, wc = wid & 1;

  if (tid < 128) {
#pragma unroll
    for (int m = 0; m < NMOD; ++m) {
      aRs[m][tid] = a_tab[m * N_PAT + brow + tid];
      bRs[m][tid] = b_tab[m * N_PAT + brow + tid];
      aCs[m][tid] = a_tab[m * N_PAT + bcol + tid];
      bCs[m][tid] = b_tab[m * N_PAT + bcol + tid];
    }
  }

  const f32x4 zero = {0.f, 0.f, 0.f, 0.f};
  f32x4 acc[4][4];
#pragma unroll
  for (int a = 0; a < 4; ++a)
#pragma unroll
    for (int b = 0; b < 4; ++b) acc[a][b] = zero;

  for (int k = 0; k < KDIM; k += 32) {
    __syncthreads();                          // LDS reuse fence (also covers ab-tables 1st iter)
#pragma unroll
    for (int t = 0; t < 2; ++t) {
      int q = tid + t * 256;                  // 512 slots of 16B per tile
      int r = q >> 2, cs = q & 3;
      const u16* gA = Y + (size_t)(brow + r) * KDIM + k + cs * 8;
      const u16* gB = Y + (size_t)(bcol + r) * KDIM + k + cs * 8;
      __builtin_amdgcn_global_load_lds(
          (const __attribute__((address_space(1))) void*)gA,
          (__attribute__((address_space(3))) void*)(&At[q * 8]), 16, 0, 0);
      __builtin_amdgcn_global_load_lds(
          (const __attribute__((address_space(1))) void*)gB,
          (__attribute__((address_space(3))) void*)(&Bt[q * 8]), 16, 0, 0);
    }
    __syncthreads();                          // drains vmcnt before reads

    bf16x8 af[4], bfv[4];
#pragma unroll
    for (int mi = 0; mi < 4; ++mi) {
      int r = wr * 64 + mi * 16 + (lane & 15);
      af[mi] = *(const bf16x8*)(&At[r * 32 + (lane >> 4) * 8]);
    }
#pragma unroll
    for (int ni = 0; ni < 4; ++ni) {
      int c = wc * 64 + ni * 16 + (lane & 15);
      bfv[ni] = *(const bf16x8*)(&Bt[c * 32 + (lane >> 4) * 8]);
    }
#pragma unroll
    for (int mi = 0; mi < 4; ++mi)
#pragma unroll
      for (int ni = 0; ni < 4; ++ni)
        acc[mi][ni] = __builtin_amdgcn_mfma_f32_16x16x32_bf16(
            af[mi], bfv[ni], acc[mi][ni], 0, 0, 0);
  }

  // Epilogue: term(i,j) = relu(M - msim + psim_ij), + mirrored term for off-diag tiles
  float Mv = Mp[0];
  float lsum = 0.0f;
  bool offd = (bx != by);
#pragma unroll
  for (int mi = 0; mi < 4; ++mi) {
#pragma unroll
    for (int ni = 0; ni < 4; ++ni) {
#pragma unroll
      for (int j = 0; j < 4; ++j) {
        int il = wr * 64 + mi * 16 + ((lane >> 4) << 2) + j;  // C row (local)
        int jl = wc * 64 + ni * 16 + (lane & 15);             // C col (local)
        float msim = acc[mi][ni][j];
        float p1 = 0.f;
#pragma unroll
        for (int m = 0; m < NMOD; ++m) p1 += aRs[m][il] * bCs[m][jl];
        float t1 = Mv - msim + p1;
        if ((brow + il) != (bcol + jl) && t1 > 0.f) lsum += t1;
        if (offd) {
          float p2 = 0.f;
#pragma unroll
          for (int m = 0; m < NMOD; ++m) p2 += aCs[m][jl] * bRs[m][il];
          float t2 = Mv - msim + p2;
          if (t2 > 0.f) lsum += t2;
        }
      }
    }
  }
#pragma unroll
  for (int o = 32; o; o >>= 1) lsum += __shfl_xor(lsum, o, 64);
  if (lane == 0) redbuf[wid] = lsum;
  __syncthreads();
  if (tid == 0) partials[p] = redbuf[0] + redbuf[1] + redbuf[2] + redbuf[3];
}

// ---------------------------------------------------------------------------
// finalize: cox = -sum(ev*(h - log(sumexp)))/sum(ev); out = cox + sum(partials)
// ---------------------------------------------------------------------------
__global__ __launch_bounds__(256) void finalize_kernel(
    const float* __restrict__ h, const int* __restrict__ ev,
    const float* __restrict__ sumexp, const float* __restrict__ partials,
    float* __restrict__ out)
{
  __shared__ float rb[12];
  int tid = threadIdx.x, lane = tid & 63, wid = tid >> 6;
  float num = 0.f, den = 0.f, sim = 0.f;
  for (int i = tid; i < N_PAT; i += 256) {
    float e = (float)ev[i];
    num += e * (h[i] - logf(sumexp[i]));
    den += e;
  }
  for (int q = tid; q < NPAIR; q += 256) sim += partials[q];
#pragma unroll
  for (int o = 32; o; o >>= 1) {
    num += __shfl_xor(num, o, 64);
    den += __shfl_xor(den, o, 64);
    sim += __shfl_xor(sim, o, 64);
  }
  if (lane == 0) { rb[wid] = num; rb[4 + wid] = den; rb[8 + wid] = sim; }
  __syncthreads();
  if (tid == 0) {
    float n = rb[0] + rb[1] + rb[2] + rb[3];
    float d = rb[4] + rb[5] + rb[6] + rb[7];
    float s = rb[8] + rb[9] + rb[10] + rb[11];
    out[0] = -n / d + s;
  }
}

// ---------------------------------------------------------------------------
extern "C" void kernel_launch(void* const* d_in, const int* in_sizes, int n_in,
                              void* d_out, int out_size, void* d_ws, size_t ws_size,
                              hipStream_t stream)
{
  const float* h  = (const float*)d_in[0];
  const float* eb = (const float*)d_in[1];
  const float* tm = (const float*)d_in[2];
  const int*   ev = (const int*)d_in[3];
  const float* Mp = (const float*)d_in[4];
  float* out = (float*)d_out;

  char* ws = (char*)d_ws;
  u16*   Y        = (u16*)ws;                                   // 8 MB
  float* a_tab    = (float*)(ws + (size_t)8 * 1024 * 1024);     // 64 KB
  float* b_tab    = a_tab + NMOD * N_PAT;                       // 64 KB
  float* sumexp   = b_tab + NMOD * N_PAT;                       // 16 KB
  float* partials = sumexp + N_PAT;                             // 528 floats
  float* eh       = partials + 1024;                            // 16 KB

  prep_kernel<<<dim3(N_PAT * NMOD / 4), dim3(256), 0, stream>>>(eb, h, Y, a_tab, b_tab, eh);
  cox_sumexp_kernel<<<dim3(N_PAT / 4), dim3(256), 0, stream>>>(tm, eh, sumexp);
  gemm_sim_kernel<<<dim3(NPAIR), dim3(256), 0, stream>>>(Y, a_tab, b_tab, Mp, partials);
  finalize_kernel<<<dim3(1), dim3(256), 0, stream>>>(h, ev, sumexp, partials, out);
}